// Round 13
// baseline (621.292 us; speedup 1.0000x reference)
//
#include <hip/hip_runtime.h>

#define EMBED 1024
#define MLP   2048
#define MLP2  4096                      // interleaved w1|w3 N-dim
#define NE    8
#define NTOK  8192                      // 4*2048 tokens
#define RMAX  (2*NTOK + NE*256)         // 18432 rows max (256-pad per expert)

typedef _Float16 f16x8 __attribute__((ext_vector_type(8)));
typedef _Float16 f16x4 __attribute__((ext_vector_type(4)));
typedef float    f32x4 __attribute__((ext_vector_type(4)));

// Async 16B global->LDS copy. LDS dest is wave-uniform base + lane*16 (HW
// constraint); we permute WHICH global chunk each lane fetches (XOR swizzle).
__device__ __forceinline__ void async_copy16(const void* g, void* l) {
  __builtin_amdgcn_global_load_lds(
      (const __attribute__((address_space(1))) unsigned int*)g,
      (__attribute__((address_space(3))) unsigned int*)l, 16, 0, 0);
}

// ---------------------------------------------------------------------------
// Router: one wave per token. logits = x[t] @ gate_w (fp32), top-2, weights =
// softmax over the two selected logits (== renormalized full softmax).
// ---------------------------------------------------------------------------
__global__ __launch_bounds__(256) void router_kernel(
    const float* __restrict__ x, const float* __restrict__ gw,
    int* __restrict__ sel_e, float* __restrict__ sel_w, int* __restrict__ counts)
{
  __shared__ float gwt[NE * EMBED];   // transposed gate: gwt[e][i]
  __shared__ int cnt[NE];
  int tid = threadIdx.x;
  for (int idx = tid; idx < NE * EMBED; idx += 256) {
    int i = idx >> 3, e = idx & 7;
    gwt[e * EMBED + i] = gw[idx];     // gw is [EMBED][NE]
  }
  if (tid < NE) cnt[tid] = 0;
  __syncthreads();

  int lane = tid & 63, wv = tid >> 6;
  int t = blockIdx.x * 4 + wv;
  const float4* xr = (const float4*)(x + (size_t)t * EMBED);
  const float4* gt4 = (const float4*)gwt;
  float acc[NE];
  #pragma unroll
  for (int e = 0; e < NE; ++e) acc[e] = 0.f;
  #pragma unroll
  for (int c = 0; c < 4; ++c) {
    float4 xv = xr[c * 64 + lane];
    #pragma unroll
    for (int e = 0; e < NE; ++e) {
      float4 gv = gt4[e * 256 + c * 64 + lane];
      acc[e] += xv.x * gv.x + xv.y * gv.y + xv.z * gv.z + xv.w * gv.w;
    }
  }
  #pragma unroll
  for (int off = 1; off < 64; off <<= 1) {
    #pragma unroll
    for (int e = 0; e < NE; ++e) acc[e] += __shfl_xor(acc[e], off);
  }
  if (lane == 0) {
    int e0 = 0; float l0 = acc[0];
    #pragma unroll
    for (int e = 1; e < NE; ++e) if (acc[e] > l0) { l0 = acc[e]; e0 = e; }
    int e1 = -1; float l1 = -1e30f;
    #pragma unroll
    for (int e = 0; e < NE; ++e) if (e != e0 && acc[e] > l1) { l1 = acc[e]; e1 = e; }
    float w0 = 1.f / (1.f + expf(l1 - l0));   // softmax over {l0,l1}
    sel_e[2 * t] = e0;     sel_w[2 * t] = w0;
    sel_e[2 * t + 1] = e1; sel_w[2 * t + 1] = 1.f - w0;
    atomicAdd(&cnt[e0], 1); atomicAdd(&cnt[e1], 1);
  }
  __syncthreads();
  if (tid < NE && cnt[tid]) atomicAdd(&counts[tid], cnt[tid]);
}

// ---------------------------------------------------------------------------
// Assign: scatter (token, weight) into per-expert row lists + inverse map.
// Segment starts are 256-aligned (GEMM row-tiles are 256). Block 0 publishes
// offs; cursor is zero-based per segment.
// ---------------------------------------------------------------------------
__global__ __launch_bounds__(256) void assign_kernel(
    const int* __restrict__ sel_e, const float* __restrict__ sel_w,
    const int* __restrict__ counts, int* __restrict__ cursor,
    int* __restrict__ offs_out, int* __restrict__ rowtok,
    float* __restrict__ rowcoef, int* __restrict__ inv)
{
  int offl[NE];
  {
    int o = 0;
    #pragma unroll
    for (int e = 0; e < NE; ++e) { offl[e] = o; o += (counts[e] + 255) & ~255; }
    if (blockIdx.x == 0 && threadIdx.x == 0) {
      #pragma unroll
      for (int e = 0; e < NE; ++e) offs_out[e] = offl[e];
      offs_out[NE] = o;
    }
  }
  int t = blockIdx.x * 256 + threadIdx.x;
  int lane = threadIdx.x & 63;
  #pragma unroll
  for (int k = 0; k < 2; ++k) {
    int e = sel_e[2 * t + k];
    float w = sel_w[2 * t + k];
    for (int xch = 0; xch < NE; ++xch) {
      unsigned long long m = __ballot(e == xch);
      if (e == xch) {
        int leader = __ffsll((unsigned long long)m) - 1;
        int base = 0;
        if (lane == leader) base = atomicAdd(&cursor[xch], (int)__popcll(m));
        base = __shfl(base, leader);
        int pos = offl[xch] + base + (int)__popcll(m & ((1ull << lane) - 1));
        rowtok[pos] = t;
        rowcoef[pos] = w;
        inv[2 * t + k] = pos;
      }
    }
  }
}

// ---------------------------------------------------------------------------
// Gather: xg[row] = fp16(x[rowtok[row]]); zeros for padding rows (tok = -1).
// ---------------------------------------------------------------------------
__global__ __launch_bounds__(256) void gather_kernel(
    const float* __restrict__ x, const int* __restrict__ rowtok,
    _Float16* __restrict__ xg)
{
  int r = blockIdx.x;
  int tok = rowtok[r];
  int t4 = threadIdx.x * 4;
  _Float16* dst = xg + (size_t)r * EMBED + t4;
  if (tok >= 0) {
    float4 v = *(const float4*)(x + (size_t)tok * EMBED + t4);
    f16x4 h; h.x = (_Float16)v.x; h.y = (_Float16)v.y; h.z = (_Float16)v.z; h.w = (_Float16)v.w;
    *(f16x4*)dst = h;
  } else {
    f16x4 z = {(_Float16)0.f, (_Float16)0.f, (_Float16)0.f, (_Float16)0.f};
    *(f16x4*)dst = z;
  }
}

// ---------------------------------------------------------------------------
// Transpose+cast all three weight tensors in ONE launch.
// fp32 [E][K][N] -> fp16 [E][N][K]. 512 64x64 tiles per (matrix, expert).
// w1 and w3 interleave into ONE tensor w13t [E][4096][1024]: 16-col groups
// alternate (verified in R6). gemm1 epilogue pairs g/u in-register.
// ---------------------------------------------------------------------------
__global__ __launch_bounds__(256) void transpose_all_kernel(
    const float* __restrict__ w1, const float* __restrict__ w3,
    const float* __restrict__ w2, _Float16* __restrict__ w13t,
    _Float16* __restrict__ w2t)
{
  int id = blockIdx.x;            // 3 * 8 * 512
  int mat = id >> 12;             // 4096 blocks per matrix
  int rr = id & 4095;
  int e = rr >> 9, tile = rr & 511;
  const float* src; _Float16* dst; int K, N; size_t estride;
  if (mat == 0)      { src = w1; dst = w13t; K = EMBED; N = MLP; estride = (size_t)MLP2 * EMBED; }
  else if (mat == 1) { src = w3; dst = w13t; K = EMBED; N = MLP; estride = (size_t)MLP2 * EMBED; }
  else               { src = w2; dst = w2t;  K = MLP;   N = EMBED; estride = (size_t)MLP * EMBED; }
  int nx = K >> 6;
  int k0 = (tile % nx) * 64, n0 = (tile / nx) * 64;
  src += (size_t)e * K * N;
  dst += (size_t)e * estride;

  __shared__ float tilebuf[64][65];
  int t = threadIdx.x;
  int r = t >> 4, c4 = (t & 15) * 4;
  #pragma unroll
  for (int i = 0; i < 4; ++i) {
    float4 v = *(const float4*)(src + (size_t)(k0 + r + 16 * i) * N + n0 + c4);
    tilebuf[r + 16 * i][c4 + 0] = v.x;
    tilebuf[r + 16 * i][c4 + 1] = v.y;
    tilebuf[r + 16 * i][c4 + 2] = v.z;
    tilebuf[r + 16 * i][c4 + 3] = v.w;
  }
  __syncthreads();
  int kk8 = (t & 7) * 8, nIdx = t >> 3;
  #pragma unroll
  for (int i = 0; i < 2; ++i) {
    int n = nIdx + 32 * i;
    f16x8 h;
    #pragma unroll
    for (int j = 0; j < 8; ++j) h[j] = (_Float16)tilebuf[kk8 + j][n];
    int nn = n0 + n;                 // source col index
    size_t drow;
    if (mat == 2) drow = nn;
    else          drow = 2 * (nn & ~15) + (nn & 15) + (mat == 1 ? 16 : 0);
    *(f16x8*)(dst + drow * K + k0 + kk8) = h;
  }
}

// ---------------------------------------------------------------------------
__device__ __forceinline__ int resolve_expert(const int* __restrict__ offs, int r0)
{
  int e = 0;
  #pragma unroll
  for (int q = 0; q < NE - 1; ++q) if (r0 >= offs[q + 1]) e = q + 1;
  return e;
}

// XCD-chunked bijective block swizzle for grid.x = 72 (nwg % 8 == 0 for
// grid.y in {4, 16}). XCD k owns x-tiles [9k, 9k+9); x varies fastest.
__device__ __forceinline__ void swz72(int& x, int& y)
{
  int lin = blockIdx.y * 72 + blockIdx.x;
  int xcd = lin & 7, idx = lin >> 3;
  x = xcd * 9 + idx % 9;
  y = idx / 9;
}

// ---------------------------------------------------------------------------
// Phase-scheduled 256x256 GEMM, R13: FINE 4-phase K-step (m201 rhythm).
// 512 threads / 8 waves as 2M x 4N; wave tile 128x64; acc[8][4] f32x4.
// BK=64, double-buffered LDS 128 KB, st-swizzle c_phys = c_log ^ (row&7)
// (stage pre-swizzles the GLOBAL source per lane; LDS dest stays linear).
//
// Per K-step t, 4 phases, each {stage 1 half-tile (2 gload_lds) -> phase
// ds_reads -> s_barrier -> lgkmcnt(0) -> setprio(1) -> 16 MFMA -> setprio(0)
// -> s_barrier}:
//   P0: stage A-h0(t+1); vmcnt(2) CERTIFIES step t (the 2 in flight are the
//       ops just issued; t's 8 are drained); reads afL(8)+bfA(4); i0-3 x j0-1
//   P1: stage A-h1(t+1); reads bfB(4);  i0-3 x j2-3
//   P2: stage B-h0(t+1); reads afH(8);  i4-7 x j2-3
//   P3: stage B-h1(t+1); no reads;      i4-7 x j0-1
// Race audit: last read of cur is P2; P2's lgkm0+barrier precede any t+1
// stage issue into cur. vmcnt never 0 mid-loop (m218 counted-vmcnt lever);
// 16-MFMA clusters with phase-local lgkm waits (m196 fine-interleave lever).
// ---------------------------------------------------------------------------

// GEMM1 (fused SwiGLU via interleaved w13t). Epilogue pairs (j even = g,
// j odd = u) per R6-verified map.
__global__ __launch_bounds__(512, 2) void gemm1_kernel(
    const _Float16* __restrict__ xg, const _Float16* __restrict__ w13t,
    const float* __restrict__ rowcoef, const int* __restrict__ offs,
    _Float16* __restrict__ hb)
{
  int bx, by; swz72(bx, by);
  int r0 = bx * 256;
  if (r0 >= offs[NE]) return;
  int e = resolve_expert(offs, r0);
  int n0 = by * 256;                 // w13-row space [0, 4096)
  const _Float16* Bw = w13t + (size_t)e * MLP2 * EMBED;

  __shared__ __align__(16) _Float16 As[2][256 * 64];   // 64 KB
  __shared__ __align__(16) _Float16 Bs[2][256 * 64];   // 64 KB

  int tid = threadIdx.x, lane = tid & 63, wv = tid >> 6;   // 8 waves
  int wm = (wv & 1) << 7;            // 0 / 128
  int wn = (wv >> 1) << 6;           // 0 / 64 / 128 / 192
  int l16 = lane & 15, quad = lane >> 4;

  int lc   = (lane & 7) ^ (lane >> 3);                     // logical chunk
  int loff = (lane >> 3) * EMBED + (lc << 3);              // f16 units
  int lrow = wv * 8;                                       // wave row base
  char* As0 = (char*)&As[0][0]; char* As1 = (char*)&As[1][0];
  char* Bs0 = (char*)&Bs[0][0]; char* Bs1 = (char*)&Bs[1][0];

  f32x4 acc[8][4];
  f32x4 z4 = {0.f, 0.f, 0.f, 0.f};
  #pragma unroll
  for (int i = 0; i < 8; ++i)
    #pragma unroll
    for (int j = 0; j < 4; ++j) acc[i][j] = z4;

  auto stageA = [&](char* dst, int kt, int o) {
    const _Float16* g = xg + (size_t)(r0 + o * 64 + lrow) * EMBED + kt * 64 + loff;
    async_copy16(g, dst + (o * 64 + lrow) * 128);
  };
  auto stageB = [&](char* dst, int kt, int o) {
    const _Float16* g = Bw + (size_t)(n0 + o * 64 + lrow) * EMBED + kt * 64 + loff;
    async_copy16(g, dst + (o * 64 + lrow) * 128);
  };
  auto frag = [&](const char* buf, int row, int clog) -> f16x8 {
    return *(const f16x8*)(buf + row * 128 + (((clog ^ (row & 7))) << 4));
  };

  const int NSTEP = EMBED / 64;      // 16
  #pragma unroll
  for (int o = 0; o < 4; ++o) { stageA(As0, 0, o); stageB(Bs0, 0, o); }

  char* Ac = As0; char* An = As1; char* Bc = Bs0; char* Bn = Bs1;
  for (int t = 0; t < NSTEP; ++t) {
    bool pf = (t + 1 < NSTEP);
    f16x8 afL[8], afH[8], bfA[4], bfB[4];
    // ---- P0 ----
    if (pf) {
      stageA(An, t + 1, 0); stageA(An, t + 1, 1);
      asm volatile("s_waitcnt vmcnt(2)" ::: "memory");   // step t certified
    } else {
      asm volatile("s_waitcnt vmcnt(0)" ::: "memory");
    }
    asm volatile("s_barrier" ::: "memory");
    #pragma unroll
    for (int i = 0; i < 4; ++i) {
      afL[2 * i]     = frag(Ac, wm + 16 * i + l16, quad);
      afL[2 * i + 1] = frag(Ac, wm + 16 * i + l16, 4 + quad);
    }
    #pragma unroll
    for (int j = 0; j < 2; ++j) {
      bfA[2 * j]     = frag(Bc, wn + 16 * j + l16, quad);
      bfA[2 * j + 1] = frag(Bc, wn + 16 * j + l16, 4 + quad);
    }
    asm volatile("s_waitcnt lgkmcnt(0)" ::: "memory");
    __builtin_amdgcn_s_setprio(1);
    #pragma unroll
    for (int i = 0; i < 4; ++i)
      #pragma unroll
      for (int j = 0; j < 2; ++j) {
        acc[i][j] = __builtin_amdgcn_mfma_f32_16x16x32_f16(afL[2 * i], bfA[2 * j], acc[i][j], 0, 0, 0);
        acc[i][j] = __builtin_amdgcn_mfma_f32_16x16x32_f16(afL[2 * i + 1], bfA[2 * j + 1], acc[i][j], 0, 0, 0);
      }
    __builtin_amdgcn_s_setprio(0);
    asm volatile("s_barrier" ::: "memory");
    // ---- P1 ----
    if (pf) { stageA(An, t + 1, 2); stageA(An, t + 1, 3); }
    #pragma unroll
    for (int j = 0; j < 2; ++j) {
      bfB[2 * j]     = frag(Bc, wn + 16 * (j + 2) + l16, quad);
      bfB[2 * j + 1] = frag(Bc, wn + 16 * (j + 2) + l16, 4 + quad);
    }
    asm volatile("s_barrier" ::: "memory");
    asm volatile("s_waitcnt lgkmcnt(0)" ::: "memory");
    __builtin_amdgcn_s_setprio(1);
    #pragma unroll
    for (int i = 0; i < 4; ++i)
      #pragma unroll
      for (int j = 0; j < 2; ++j) {
        acc[i][j + 2] = __builtin_amdgcn_mfma_f32_16x16x32_f16(afL[2 * i], bfB[2 * j], acc[i][j + 2], 0, 0, 0);
        acc[i][j + 2] = __builtin_amdgcn_mfma_f32_16x16x32_f16(afL[2 * i + 1], bfB[2 * j + 1], acc[i][j + 2], 0, 0, 0);
      }
    __builtin_amdgcn_s_setprio(0);
    asm volatile("s_barrier" ::: "memory");
    // ---- P2 ----
    if (pf) { stageB(Bn, t + 1, 0); stageB(Bn, t + 1, 1); }
    #pragma unroll
    for (int i = 0; i < 4; ++i) {
      afH[2 * i]     = frag(Ac, wm + 16 * (i + 4) + l16, quad);
      afH[2 * i + 1] = frag(Ac, wm + 16 * (i + 4) + l16, 4 + quad);
    }
    asm volatile("s_barrier" ::: "memory");
    asm volatile("s_waitcnt lgkmcnt(0)" ::: "memory");
    __builtin_amdgcn_s_setprio(1);
    #pragma unroll
    for (int i = 0; i < 4; ++i)
      #pragma unroll
      for (int j = 0; j < 2; ++j) {
        acc[i + 4][j + 2] = __builtin_amdgcn_mfma_f32_16x16x32_f16(afH[2 * i], bfB[2 * j], acc[i + 4][j + 2], 0, 0, 0);
        acc[i + 4][j + 2] = __builtin_amdgcn_mfma_f32_16x16x32_f16(afH[2 * i + 1], bfB[2 * j + 1], acc[i + 4][j + 2], 0, 0, 0);
      }
    __builtin_amdgcn_s_setprio(0);
    asm volatile("s_barrier" ::: "memory");
    // ---- P3 ----
    if (pf) { stageB(Bn, t + 1, 2); stageB(Bn, t + 1, 3); }
    asm volatile("s_barrier" ::: "memory");
    __builtin_amdgcn_s_setprio(1);
    #pragma unroll
    for (int i = 0; i < 4; ++i)
      #pragma unroll
      for (int j = 0; j < 2; ++j) {
        acc[i + 4][j] = __builtin_amdgcn_mfma_f32_16x16x32_f16(afH[2 * i], bfA[2 * j], acc[i + 4][j], 0, 0, 0);
        acc[i + 4][j] = __builtin_amdgcn_mfma_f32_16x16x32_f16(afH[2 * i + 1], bfA[2 * j + 1], acc[i + 4][j], 0, 0, 0);
      }
    __builtin_amdgcn_s_setprio(0);
    asm volatile("s_barrier" ::: "memory");

    char* tmp;
    tmp = Ac; Ac = An; An = tmp;
    tmp = Bc; Bc = Bn; Bn = tmp;
  }

  // Epilogue: j even = g (w1), j odd = u (w3), same lane/reg (R6-verified).
  int colbase = (((n0 + wn) >> 5) << 4) + l16;
  #pragma unroll
  for (int i = 0; i < 8; ++i) {
    int mb = r0 + wm + 16 * i + quad * 4;
    float cf[4];
    #pragma unroll
    for (int rg = 0; rg < 4; ++rg) cf[rg] = rowcoef[mb + rg];
    #pragma unroll
    for (int p = 0; p < 2; ++p) {
      int col = colbase + 16 * p;
      #pragma unroll
      for (int rg = 0; rg < 4; ++rg) {
        float g = acc[i][2 * p][rg], u = acc[i][2 * p + 1][rg];
        float h = g * u * cf[rg] / (1.f + __expf(-g));
        hb[(size_t)(mb + rg) * MLP + col] = (_Float16)h;
      }
    }
  }
}

// ---------------------------------------------------------------------------
// GEMM2: hb2[row] = h[row] @ w2t^T. Same fine 4-phase template, K=2048
// (32 steps), N=1024 (grid.y = 4). Standard epilogue.
// ---------------------------------------------------------------------------
__global__ __launch_bounds__(512, 2) void gemm2_kernel(
    const _Float16* __restrict__ hb, const _Float16* __restrict__ w2t,
    const int* __restrict__ offs, _Float16* __restrict__ hb2)
{
  int bx, by; swz72(bx, by);
  int r0 = bx * 256;
  if (r0 >= offs[NE]) return;
  int e = resolve_expert(offs, r0);
  int n0 = by * 256;
  const _Float16* Bw = w2t + (size_t)e * EMBED * MLP;

  __shared__ __align__(16) _Float16 As[2][256 * 64];   // 64 KB
  __shared__ __align__(16) _Float16 Bs[2][256 * 64];   // 64 KB

  int tid = threadIdx.x, lane = tid & 63, wv = tid >> 6;
  int wm = (wv & 1) << 7;
  int wn = (wv >> 1) << 6;
  int l16 = lane & 15, quad = lane >> 4;

  int lc   = (lane & 7) ^ (lane >> 3);
  int loff = (lane >> 3) * MLP + (lc << 3);
  int lrow = wv * 8;
  char* As0 = (char*)&As[0][0]; char* As1 = (char*)&As[1][0];
  char* Bs0 = (char*)&Bs[0][0]; char* Bs1 = (char*)&Bs[1][0];

  f32x4 acc[8][4];
  f32x4 z4 = {0.f, 0.f, 0.f, 0.f};
  #pragma unroll
  for (int i = 0; i < 8; ++i)
    #pragma unroll
    for (int j = 0; j < 4; ++j) acc[i][j] = z4;

  auto stageA = [&](char* dst, int kt, int o) {
    const _Float16* g = hb + (size_t)(r0 + o * 64 + lrow) * MLP + kt * 64 + loff;
    async_copy16(g, dst + (o * 64 + lrow) * 128);
  };
  auto stageB = [&](char* dst, int kt, int o) {
    const _Float16* g = Bw + (size_t)(n0 + o * 64 + lrow) * MLP + kt * 64 + loff;
    async_copy16(g, dst + (o * 64 + lrow) * 128);
  };
  auto frag = [&](const char* buf, int row, int clog) -> f16x8 {
    return *(const f16x8*)(buf + row * 128 + (((clog ^ (row & 7))) << 4));
  };

  const int NSTEP = MLP / 64;        // 32
  #pragma unroll
  for (int o = 0; o < 4; ++o) { stageA(As0, 0, o); stageB(Bs0, 0, o); }

  char* Ac = As0; char* An = As1; char* Bc = Bs0; char* Bn = Bs1;
  for (int t = 0; t < NSTEP; ++t) {
    bool pf = (t + 1 < NSTEP);
    f16x8 afL[8], afH[8], bfA[4], bfB[4];
    // ---- P0 ----
    if (pf) {
      stageA(An, t + 1, 0); stageA(An, t + 1, 1);
      asm volatile("s_waitcnt vmcnt(2)" ::: "memory");
    } else {
      asm volatile("s_waitcnt vmcnt(0)" ::: "memory");
    }
    asm volatile("s_barrier" ::: "memory");
    #pragma unroll
    for (int i = 0; i < 4; ++i) {
      afL[2 * i]     = frag(Ac, wm + 16 * i + l16, quad);
      afL[2 * i + 1] = frag(Ac, wm + 16 * i + l16, 4 + quad);
    }
    #pragma unroll
    for (int j = 0; j < 2; ++j) {
      bfA[2 * j]     = frag(Bc, wn + 16 * j + l16, quad);
      bfA[2 * j + 1] = frag(Bc, wn + 16 * j + l16, 4 + quad);
    }
    asm volatile("s_waitcnt lgkmcnt(0)" ::: "memory");
    __builtin_amdgcn_s_setprio(1);
    #pragma unroll
    for (int i = 0; i < 4; ++i)
      #pragma unroll
      for (int j = 0; j < 2; ++j) {
        acc[i][j] = __builtin_amdgcn_mfma_f32_16x16x32_f16(afL[2 * i], bfA[2 * j], acc[i][j], 0, 0, 0);
        acc[i][j] = __builtin_amdgcn_mfma_f32_16x16x32_f16(afL[2 * i + 1], bfA[2 * j + 1], acc[i][j], 0, 0, 0);
      }
    __builtin_amdgcn_s_setprio(0);
    asm volatile("s_barrier" ::: "memory");
    // ---- P1 ----
    if (pf) { stageA(An, t + 1, 2); stageA(An, t + 1, 3); }
    #pragma unroll
    for (int j = 0; j < 2; ++j) {
      bfB[2 * j]     = frag(Bc, wn + 16 * (j + 2) + l16, quad);
      bfB[2 * j + 1] = frag(Bc, wn + 16 * (j + 2) + l16, 4 + quad);
    }
    asm volatile("s_barrier" ::: "memory");
    asm volatile("s_waitcnt lgkmcnt(0)" ::: "memory");
    __builtin_amdgcn_s_setprio(1);
    #pragma unroll
    for (int i = 0; i < 4; ++i)
      #pragma unroll
      for (int j = 0; j < 2; ++j) {
        acc[i][j + 2] = __builtin_amdgcn_mfma_f32_16x16x32_f16(afL[2 * i], bfB[2 * j], acc[i][j + 2], 0, 0, 0);
        acc[i][j + 2] = __builtin_amdgcn_mfma_f32_16x16x32_f16(afL[2 * i + 1], bfB[2 * j + 1], acc[i][j + 2], 0, 0, 0);
      }
    __builtin_amdgcn_s_setprio(0);
    asm volatile("s_barrier" ::: "memory");
    // ---- P2 ----
    if (pf) { stageB(Bn, t + 1, 0); stageB(Bn, t + 1, 1); }
    #pragma unroll
    for (int i = 0; i < 4; ++i) {
      afH[2 * i]     = frag(Ac, wm + 16 * (i + 4) + l16, quad);
      afH[2 * i + 1] = frag(Ac, wm + 16 * (i + 4) + l16, 4 + quad);
    }
    asm volatile("s_barrier" ::: "memory");
    asm volatile("s_waitcnt lgkmcnt(0)" ::: "memory");
    __builtin_amdgcn_s_setprio(1);
    #pragma unroll
    for (int i = 0; i < 4; ++i)
      #pragma unroll
      for (int j = 0; j < 2; ++j) {
        acc[i + 4][j + 2] = __builtin_amdgcn_mfma_f32_16x16x32_f16(afH[2 * i], bfB[2 * j], acc[i + 4][j + 2], 0, 0, 0);
        acc[i + 4][j + 2] = __builtin_amdgcn_mfma_f32_16x16x32_f16(afH[2 * i + 1], bfB[2 * j + 1], acc[i + 4][j + 2], 0, 0, 0);
      }
    __builtin_amdgcn_s_setprio(0);
    asm volatile("s_barrier" ::: "memory");
    // ---- P3 ----
    if (pf) { stageB(Bn, t + 1, 2); stageB(Bn, t + 1, 3); }
    asm volatile("s_barrier" ::: "memory");
    __builtin_amdgcn_s_setprio(1);
    #pragma unroll
    for (int i = 0; i < 4; ++i)
      #pragma unroll
      for (int j = 0; j < 2; ++j) {
        acc[i + 4][j] = __builtin_amdgcn_mfma_f32_16x16x32_f16(afH[2 * i], bfA[2 * j], acc[i + 4][j], 0, 0, 0);
        acc[i + 4][j] = __builtin_amdgcn_mfma_f32_16x16x32_f16(afH[2 * i + 1], bfA[2 * j + 1], acc[i + 4][j], 0, 0, 0);
      }
    __builtin_amdgcn_s_setprio(0);
    asm volatile("s_barrier" ::: "memory");

    char* tmp;
    tmp = Ac; Ac = An; An = tmp;
    tmp = Bc; Bc = Bn; Bn = tmp;
  }

  #pragma unroll
  for (int i = 0; i < 8; ++i) {
    int mb = r0 + wm + 16 * i + quad * 4;
    #pragma unroll
    for (int j = 0; j < 4; ++j) {
      int col = n0 + wn + 16 * j + l16;
      #pragma unroll
      for (int rg = 0; rg < 4; ++rg)
        hb2[(size_t)(mb + rg) * EMBED + col] = (_Float16)acc[i][j][rg];
    }
  }
}

// ---------------------------------------------------------------------------
// Combine: out[t] = hb2[inv[2t]] + hb2[inv[2t+1]] (fp32 out).
// ---------------------------------------------------------------------------
__global__ __launch_bounds__(256) void combine_kernel(
    const _Float16* __restrict__ hb2, const int* __restrict__ inv,
    float* __restrict__ out)
{
  int t = blockIdx.x;
  int d = threadIdx.x * 4;
  int p0 = inv[2 * t], p1 = inv[2 * t + 1];
  f16x4 a = *(const f16x4*)(hb2 + (size_t)p0 * EMBED + d);
  f16x4 b = *(const f16x4*)(hb2 + (size_t)p1 * EMBED + d);
  float4 r;
  r.x = (float)a.x + (float)b.x;
  r.y = (float)a.y + (float)b.y;
  r.z = (float)a.z + (float)b.z;
  r.w = (float)a.w + (float)b.w;
  *(float4*)(out + (size_t)t * EMBED + d) = r;
}

// ---------------------------------------------------------------------------
extern "C" void kernel_launch(void* const* d_in, const int* in_sizes, int n_in,
                              void* d_out, int out_size, void* d_ws, size_t ws_size,
                              hipStream_t stream)
{
  (void)in_sizes; (void)n_in; (void)ws_size; (void)out_size;
  const float* x  = (const float*)d_in[0];
  const float* gw = (const float*)d_in[1];
  const float* w1 = (const float*)d_in[2];
  const float* w2 = (const float*)d_in[3];   // NOTE: dict order is w1, w2, w3
  const float* w3 = (const float*)d_in[4];
  float* out = (float*)d_out;
  char* ws = (char*)d_ws;

  size_t o = 0;
  auto alloc = [&](size_t bytes) { size_t r = o; o = (o + bytes + 255) & ~255ULL; return r; };
  _Float16* w13t = (_Float16*)(ws + alloc((size_t)NE * MLP2 * EMBED * 2));
  _Float16* w2t  = (_Float16*)(ws + alloc((size_t)NE * MLP * EMBED * 2));
  _Float16* xg   = (_Float16*)(ws + alloc((size_t)RMAX * EMBED * 2));
  _Float16* hb   = (_Float16*)(ws + alloc((size_t)RMAX * MLP * 2));
  int*   rowtok  = (int*)(ws + alloc((size_t)RMAX * 4));
  float* rowcoef = (float*)(ws + alloc((size_t)RMAX * 4));
  int*   sel_e   = (int*)(ws + alloc((size_t)2 * NTOK * 4));
  float* sel_w   = (float*)(ws + alloc((size_t)2 * NTOK * 4));
  int*   inv     = (int*)(ws + alloc((size_t)2 * NTOK * 4));
  int*   meta    = (int*)(ws + alloc(256));
  int* counts = meta;          // [8]
  int* offs   = meta + 8;      // [9]
  int* cursor = meta + 17;     // [8] (zero-based)
  // hb2 aliases xg: xg is dead after gemm1; both are RMAX*EMBED fp16.
  _Float16* hb2 = xg;

  hipMemsetAsync(meta, 0, 256, stream);
  hipMemsetAsync(rowtok, 0xFF, (size_t)RMAX * 4, stream);   // -1 = padding
  hipMemsetAsync(rowcoef, 0, (size_t)RMAX * 4, stream);

  transpose_all_kernel<<<3 * 4096, 256, 0, stream>>>(w1, w3, w2, w13t, w2t);

  router_kernel<<<NTOK / 4, 256, 0, stream>>>(x, gw, sel_e, sel_w, counts);
  assign_kernel<<<NTOK / 256, 256, 0, stream>>>(sel_e, sel_w, counts, cursor,
                                                offs, rowtok, rowcoef, inv);
  gather_kernel<<<RMAX, 256, 0, stream>>>(x, rowtok, xg);

  gemm1_kernel<<<dim3(RMAX / 256, MLP2 / 256), 512, 0, stream>>>(xg, w13t, rowcoef, offs, hb);
  gemm2_kernel<<<dim3(RMAX / 256, EMBED / 256), 512, 0, stream>>>(hb, w2t, offs, hb2);
  combine_kernel<<<NTOK, 256, 0, stream>>>(hb2, inv, out);
}

// Round 15
// 577.760 us; speedup vs baseline: 1.0753x; 1.0753x over previous
//
#include <hip/hip_runtime.h>

#define EMBED 1024
#define MLP   2048
#define MLP2  4096                      // interleaved w1|w3 N-dim
#define NE    8
#define NTOK  8192                      // 4*2048 tokens
#define RMAX  (2*NTOK + NE*256)         // 18432 rows max (256-pad per expert)

typedef _Float16 f16x8 __attribute__((ext_vector_type(8)));
typedef _Float16 f16x4 __attribute__((ext_vector_type(4)));
typedef float    f32x4 __attribute__((ext_vector_type(4)));

// Async 16B global->LDS copy. LDS dest is wave-uniform base + lane*16 (HW
// constraint); we permute WHICH global chunk each lane fetches (XOR swizzle).
__device__ __forceinline__ void async_copy16(const void* g, void* l) {
  __builtin_amdgcn_global_load_lds(
      (const __attribute__((address_space(1))) unsigned int*)g,
      (__attribute__((address_space(3))) unsigned int*)l, 16, 0, 0);
}

// ---------------------------------------------------------------------------
// Router: one wave per token. logits = x[t] @ gate_w (fp32), top-2, weights =
// softmax over the two selected logits (== renormalized full softmax).
// ---------------------------------------------------------------------------
__global__ __launch_bounds__(256) void router_kernel(
    const float* __restrict__ x, const float* __restrict__ gw,
    int* __restrict__ sel_e, float* __restrict__ sel_w, int* __restrict__ counts)
{
  __shared__ float gwt[NE * EMBED];   // transposed gate: gwt[e][i]
  __shared__ int cnt[NE];
  int tid = threadIdx.x;
  for (int idx = tid; idx < NE * EMBED; idx += 256) {
    int i = idx >> 3, e = idx & 7;
    gwt[e * EMBED + i] = gw[idx];     // gw is [EMBED][NE]
  }
  if (tid < NE) cnt[tid] = 0;
  __syncthreads();

  int lane = tid & 63, wv = tid >> 6;
  int t = blockIdx.x * 4 + wv;
  const float4* xr = (const float4*)(x + (size_t)t * EMBED);
  const float4* gt4 = (const float4*)gwt;
  float acc[NE];
  #pragma unroll
  for (int e = 0; e < NE; ++e) acc[e] = 0.f;
  #pragma unroll
  for (int c = 0; c < 4; ++c) {
    float4 xv = xr[c * 64 + lane];
    #pragma unroll
    for (int e = 0; e < NE; ++e) {
      float4 gv = gt4[e * 256 + c * 64 + lane];
      acc[e] += xv.x * gv.x + xv.y * gv.y + xv.z * gv.z + xv.w * gv.w;
    }
  }
  #pragma unroll
  for (int off = 1; off < 64; off <<= 1) {
    #pragma unroll
    for (int e = 0; e < NE; ++e) acc[e] += __shfl_xor(acc[e], off);
  }
  if (lane == 0) {
    int e0 = 0; float l0 = acc[0];
    #pragma unroll
    for (int e = 1; e < NE; ++e) if (acc[e] > l0) { l0 = acc[e]; e0 = e; }
    int e1 = -1; float l1 = -1e30f;
    #pragma unroll
    for (int e = 0; e < NE; ++e) if (e != e0 && acc[e] > l1) { l1 = acc[e]; e1 = e; }
    float w0 = 1.f / (1.f + expf(l1 - l0));   // softmax over {l0,l1}
    sel_e[2 * t] = e0;     sel_w[2 * t] = w0;
    sel_e[2 * t + 1] = e1; sel_w[2 * t + 1] = 1.f - w0;
    atomicAdd(&cnt[e0], 1); atomicAdd(&cnt[e1], 1);
  }
  __syncthreads();
  if (tid < NE && cnt[tid]) atomicAdd(&counts[tid], cnt[tid]);
}

// ---------------------------------------------------------------------------
// Assign: scatter (token, weight) into per-expert row lists + inverse map.
// Segment starts are 256-aligned (GEMM row-tiles are 256/128). Block 0
// publishes offs; cursor is zero-based per segment.
// ---------------------------------------------------------------------------
__global__ __launch_bounds__(256) void assign_kernel(
    const int* __restrict__ sel_e, const float* __restrict__ sel_w,
    const int* __restrict__ counts, int* __restrict__ cursor,
    int* __restrict__ offs_out, int* __restrict__ rowtok,
    float* __restrict__ rowcoef, int* __restrict__ inv)
{
  int offl[NE];
  {
    int o = 0;
    #pragma unroll
    for (int e = 0; e < NE; ++e) { offl[e] = o; o += (counts[e] + 255) & ~255; }
    if (blockIdx.x == 0 && threadIdx.x == 0) {
      #pragma unroll
      for (int e = 0; e < NE; ++e) offs_out[e] = offl[e];
      offs_out[NE] = o;
    }
  }
  int t = blockIdx.x * 256 + threadIdx.x;
  int lane = threadIdx.x & 63;
  #pragma unroll
  for (int k = 0; k < 2; ++k) {
    int e = sel_e[2 * t + k];
    float w = sel_w[2 * t + k];
    for (int xch = 0; xch < NE; ++xch) {
      unsigned long long m = __ballot(e == xch);
      if (e == xch) {
        int leader = __ffsll((unsigned long long)m) - 1;
        int base = 0;
        if (lane == leader) base = atomicAdd(&cursor[xch], (int)__popcll(m));
        base = __shfl(base, leader);
        int pos = offl[xch] + base + (int)__popcll(m & ((1ull << lane) - 1));
        rowtok[pos] = t;
        rowcoef[pos] = w;
        inv[2 * t + k] = pos;
      }
    }
  }
}

// ---------------------------------------------------------------------------
// Gather: xg[row] = fp16(x[rowtok[row]]); zeros for padding rows (tok = -1).
// ---------------------------------------------------------------------------
__global__ __launch_bounds__(256) void gather_kernel(
    const float* __restrict__ x, const int* __restrict__ rowtok,
    _Float16* __restrict__ xg)
{
  int r = blockIdx.x;
  int tok = rowtok[r];
  int t4 = threadIdx.x * 4;
  _Float16* dst = xg + (size_t)r * EMBED + t4;
  if (tok >= 0) {
    float4 v = *(const float4*)(x + (size_t)tok * EMBED + t4);
    f16x4 h; h.x = (_Float16)v.x; h.y = (_Float16)v.y; h.z = (_Float16)v.z; h.w = (_Float16)v.w;
    *(f16x4*)dst = h;
  } else {
    f16x4 z = {(_Float16)0.f, (_Float16)0.f, (_Float16)0.f, (_Float16)0.f};
    *(f16x4*)dst = z;
  }
}

// ---------------------------------------------------------------------------
// Transpose+cast all three weight tensors in ONE launch.
// fp32 [E][K][N] -> fp16 [E][N][K]. 512 64x64 tiles per (matrix, expert).
// w1 and w3 interleave into ONE tensor w13t [E][4096][1024]: 16-col groups
// alternate (verified in R6). gemm1 epilogue pairs g/u in-register.
// ---------------------------------------------------------------------------
__global__ __launch_bounds__(256) void transpose_all_kernel(
    const float* __restrict__ w1, const float* __restrict__ w3,
    const float* __restrict__ w2, _Float16* __restrict__ w13t,
    _Float16* __restrict__ w2t)
{
  int id = blockIdx.x;            // 3 * 8 * 512
  int mat = id >> 12;             // 4096 blocks per matrix
  int rr = id & 4095;
  int e = rr >> 9, tile = rr & 511;
  const float* src; _Float16* dst; int K, N; size_t estride;
  if (mat == 0)      { src = w1; dst = w13t; K = EMBED; N = MLP; estride = (size_t)MLP2 * EMBED; }
  else if (mat == 1) { src = w3; dst = w13t; K = EMBED; N = MLP; estride = (size_t)MLP2 * EMBED; }
  else               { src = w2; dst = w2t;  K = MLP;   N = EMBED; estride = (size_t)MLP * EMBED; }
  int nx = K >> 6;
  int k0 = (tile % nx) * 64, n0 = (tile / nx) * 64;
  src += (size_t)e * K * N;
  dst += (size_t)e * estride;

  __shared__ float tilebuf[64][65];
  int t = threadIdx.x;
  int r = t >> 4, c4 = (t & 15) * 4;
  #pragma unroll
  for (int i = 0; i < 4; ++i) {
    float4 v = *(const float4*)(src + (size_t)(k0 + r + 16 * i) * N + n0 + c4);
    tilebuf[r + 16 * i][c4 + 0] = v.x;
    tilebuf[r + 16 * i][c4 + 1] = v.y;
    tilebuf[r + 16 * i][c4 + 2] = v.z;
    tilebuf[r + 16 * i][c4 + 3] = v.w;
  }
  __syncthreads();
  int kk8 = (t & 7) * 8, nIdx = t >> 3;
  #pragma unroll
  for (int i = 0; i < 2; ++i) {
    int n = nIdx + 32 * i;
    f16x8 h;
    #pragma unroll
    for (int j = 0; j < 8; ++j) h[j] = (_Float16)tilebuf[kk8 + j][n];
    int nn = n0 + n;                 // source col index
    size_t drow;
    if (mat == 2) drow = nn;
    else          drow = 2 * (nn & ~15) + (nn & 15) + (mat == 1 ? 16 : 0);
    *(f16x8*)(dst + drow * K + k0 + kk8) = h;
  }
}

// ---------------------------------------------------------------------------
__device__ __forceinline__ int resolve_expert(const int* __restrict__ offs, int r0)
{
  int e = 0;
  #pragma unroll
  for (int q = 0; q < NE - 1; ++q) if (r0 >= offs[q + 1]) e = q + 1;
  return e;
}

// XCD-chunked bijective block swizzles (x varies fastest within a chunk).
__device__ __forceinline__ void swz72(int& x, int& y)   // grid.x = 72
{
  int lin = blockIdx.y * 72 + blockIdx.x;
  int xcd = lin & 7, idx = lin >> 3;
  x = xcd * 9 + idx % 9;
  y = idx / 9;
}
__device__ __forceinline__ void swz144(int& x, int& y)  // grid.x = 144
{
  int lin = blockIdx.y * 144 + blockIdx.x;
  int xcd = lin & 7, idx = lin >> 3;
  x = xcd * 18 + idx % 18;
  y = idx / 18;
}

// ---------------------------------------------------------------------------
// GEMM1 (fused SwiGLU via interleaved w13t): R12-verified schedule (best
// measured: 171 us, MfmaUtil 36.7; R13's fine 4-phase regressed -17%).
// 256x256 tile, 8 waves 2Mx4N (wave tile 128x64), BK=64, dbuf LDS 128 KB,
// chunk swizzle c_phys = c_log ^ (row&7), counted vmcnt(4), 2 barriers/step.
// ---------------------------------------------------------------------------
__global__ __launch_bounds__(512, 2) void gemm1_kernel(
    const _Float16* __restrict__ xg, const _Float16* __restrict__ w13t,
    const float* __restrict__ rowcoef, const int* __restrict__ offs,
    _Float16* __restrict__ hb)
{
  int bx, by; swz72(bx, by);
  int r0 = bx * 256;
  if (r0 >= offs[NE]) return;
  int e = resolve_expert(offs, r0);
  int n0 = by * 256;                 // w13-row space [0, 4096)
  const _Float16* Bw = w13t + (size_t)e * MLP2 * EMBED;

  __shared__ __align__(16) _Float16 As[2][256 * 64];   // 64 KB
  __shared__ __align__(16) _Float16 Bs[2][256 * 64];   // 64 KB

  int tid = threadIdx.x, lane = tid & 63, wv = tid >> 6;   // 8 waves
  int wm = (wv & 1) << 7;            // 0 / 128
  int wn = (wv >> 1) << 6;           // 0 / 64 / 128 / 192
  int l16 = lane & 15, quad = lane >> 4;

  int lc   = (lane & 7) ^ (lane >> 3);                     // logical chunk
  int loff = (lane >> 3) * EMBED + (lc << 3);              // f16 units
  int lrow = wv * 8;                                       // wave row base
  char* As0 = (char*)&As[0][0]; char* As1 = (char*)&As[1][0];
  char* Bs0 = (char*)&Bs[0][0]; char* Bs1 = (char*)&Bs[1][0];

  f32x4 acc[8][4];
  f32x4 z4 = {0.f, 0.f, 0.f, 0.f};
  #pragma unroll
  for (int i = 0; i < 8; ++i)
    #pragma unroll
    for (int j = 0; j < 4; ++j) acc[i][j] = z4;

  auto stageA = [&](char* dst, int kt, int o) {
    const _Float16* g = xg + (size_t)(r0 + o * 64 + lrow) * EMBED + kt * 64 + loff;
    async_copy16(g, dst + (o * 64 + lrow) * 128);
  };
  auto stageB = [&](char* dst, int kt, int o) {
    const _Float16* g = Bw + (size_t)(n0 + o * 64 + lrow) * EMBED + kt * 64 + loff;
    async_copy16(g, dst + (o * 64 + lrow) * 128);
  };
  auto frag = [&](const char* buf, int row, int clog) -> f16x8 {
    return *(const f16x8*)(buf + row * 128 + (((clog ^ (row & 7))) << 4));
  };

  const int NSTEP = EMBED / 64;      // 16
  #pragma unroll
  for (int o = 0; o < 4; ++o) { stageA(As0, 0, o); stageB(Bs0, 0, o); }

  char* Ac = As0; char* An = As1; char* Bc = Bs0; char* Bn = Bs1;
  for (int t = 0; t < NSTEP; ++t) {
    if (t + 1 < NSTEP) {
      #pragma unroll
      for (int o = 0; o < 4; ++o) stageA(An, t + 1, o);
      asm volatile("s_waitcnt vmcnt(4)" ::: "memory");   // tile t landed
    } else {
      asm volatile("s_waitcnt vmcnt(0)" ::: "memory");
    }
    asm volatile("s_barrier" ::: "memory");

    f16x8 af[8], bf[4];
    #pragma unroll
    for (int i = 0; i < 8; ++i) af[i] = frag(Ac, wm + 16 * i + l16, quad);
    #pragma unroll
    for (int j = 0; j < 4; ++j) bf[j] = frag(Bc, wn + 16 * j + l16, quad);
    if (t + 1 < NSTEP) {
      #pragma unroll
      for (int o = 0; o < 4; ++o) stageB(Bn, t + 1, o);
    }
    __builtin_amdgcn_s_setprio(1);
    #pragma unroll
    for (int i = 0; i < 8; ++i)
      #pragma unroll
      for (int j = 0; j < 4; ++j)
        acc[i][j] = __builtin_amdgcn_mfma_f32_16x16x32_f16(af[i], bf[j], acc[i][j], 0, 0, 0);
    __builtin_amdgcn_s_setprio(0);
    #pragma unroll
    for (int i = 0; i < 8; ++i) af[i] = frag(Ac, wm + 16 * i + l16, 4 + quad);
    #pragma unroll
    for (int j = 0; j < 4; ++j) bf[j] = frag(Bc, wn + 16 * j + l16, 4 + quad);
    asm volatile("s_waitcnt lgkmcnt(0)" ::: "memory");
    asm volatile("s_barrier" ::: "memory");
    __builtin_amdgcn_s_setprio(1);
    #pragma unroll
    for (int i = 0; i < 8; ++i)
      #pragma unroll
      for (int j = 0; j < 4; ++j)
        acc[i][j] = __builtin_amdgcn_mfma_f32_16x16x32_f16(af[i], bf[j], acc[i][j], 0, 0, 0);
    __builtin_amdgcn_s_setprio(0);

    char* tmp;
    tmp = Ac; Ac = An; An = tmp;
    tmp = Bc; Bc = Bn; Bn = tmp;
  }

  // Epilogue: j even = g (w1), j odd = u (w3), same lane/reg (R6-verified).
  int colbase = (((n0 + wn) >> 5) << 4) + l16;
  #pragma unroll
  for (int i = 0; i < 8; ++i) {
    int mb = r0 + wm + 16 * i + quad * 4;
    float cf[4];
    #pragma unroll
    for (int rg = 0; rg < 4; ++rg) cf[rg] = rowcoef[mb + rg];
    #pragma unroll
    for (int p = 0; p < 2; ++p) {
      int col = colbase + 16 * p;
      #pragma unroll
      for (int rg = 0; rg < 4; ++rg) {
        float g = acc[i][2 * p][rg], u = acc[i][2 * p + 1][rg];
        float h = g * u * cf[rg] / (1.f + __expf(-g));
        hb[(size_t)(mb + rg) * MLP + col] = (_Float16)h;
      }
    }
  }
}

// ---------------------------------------------------------------------------
// GEMM2: hb2[row] = h[row] @ w2t^T. R12 schedule, but 128x256 TILE:
// R12's 256x256 grid = 288 blocks at 1 block/CU -> 2 scheduling rounds with
// the 2nd round only 32/256 CUs busy (~44% of gemm2 wasted). 128x256 gives
// 576 blocks of half duration -> ~114-130 us (3 tight rounds).
// 8 waves as 2Mx4N, wave tile 64x64, acc[4][4]; LDS 96 KB (As 32 + Bs 64);
// 6 stage ops/K-step -> vmcnt(2) certification (prologue 6 ops; 2 A-ops at
// step top leave exactly the new 2 in flight).
// ---------------------------------------------------------------------------
__global__ __launch_bounds__(512, 2) void gemm2_kernel(
    const _Float16* __restrict__ hb, const _Float16* __restrict__ w2t,
    const int* __restrict__ offs, _Float16* __restrict__ hb2)
{
  int bx, by; swz144(bx, by);
  int r0 = bx * 128;
  if (r0 >= offs[NE]) return;
  int e = resolve_expert(offs, r0);
  int n0 = by * 256;
  const _Float16* Bw = w2t + (size_t)e * EMBED * MLP;

  __shared__ __align__(16) _Float16 As[2][128 * 64];   // 32 KB
  __shared__ __align__(16) _Float16 Bs[2][256 * 64];   // 64 KB

  int tid = threadIdx.x, lane = tid & 63, wv = tid >> 6;
  int wm = (wv & 1) << 6;            // 0 / 64
  int wn = (wv >> 1) << 6;           // 0 / 64 / 128 / 192
  int l16 = lane & 15, quad = lane >> 4;

  int lc   = (lane & 7) ^ (lane >> 3);
  int loff = (lane >> 3) * MLP + (lc << 3);
  int lrow = wv * 8;
  char* As0 = (char*)&As[0][0]; char* As1 = (char*)&As[1][0];
  char* Bs0 = (char*)&Bs[0][0]; char* Bs1 = (char*)&Bs[1][0];

  f32x4 acc[4][4];
  f32x4 z4 = {0.f, 0.f, 0.f, 0.f};
  #pragma unroll
  for (int i = 0; i < 4; ++i)
    #pragma unroll
    for (int j = 0; j < 4; ++j) acc[i][j] = z4;

  auto stageA = [&](char* dst, int kt, int o) {   // o = 0..1
    const _Float16* g = hb + (size_t)(r0 + o * 64 + lrow) * MLP + kt * 64 + loff;
    async_copy16(g, dst + (o * 64 + lrow) * 128);
  };
  auto stageB = [&](char* dst, int kt, int o) {   // o = 0..3
    const _Float16* g = Bw + (size_t)(n0 + o * 64 + lrow) * MLP + kt * 64 + loff;
    async_copy16(g, dst + (o * 64 + lrow) * 128);
  };
  auto frag = [&](const char* buf, int row, int clog) -> f16x8 {
    return *(const f16x8*)(buf + row * 128 + (((clog ^ (row & 7))) << 4));
  };

  const int NSTEP = MLP / 64;        // 32
  #pragma unroll
  for (int o = 0; o < 2; ++o) stageA(As0, 0, o);
  #pragma unroll
  for (int o = 0; o < 4; ++o) stageB(Bs0, 0, o);

  char* Ac = As0; char* An = As1; char* Bc = Bs0; char* Bn = Bs1;
  for (int t = 0; t < NSTEP; ++t) {
    if (t + 1 < NSTEP) {
      stageA(An, t + 1, 0); stageA(An, t + 1, 1);
      asm volatile("s_waitcnt vmcnt(2)" ::: "memory");   // tile t landed
    } else {
      asm volatile("s_waitcnt vmcnt(0)" ::: "memory");
    }
    asm volatile("s_barrier" ::: "memory");

    f16x8 af[4], bf[4];
    #pragma unroll
    for (int i = 0; i < 4; ++i) af[i] = frag(Ac, wm + 16 * i + l16, quad);
    #pragma unroll
    for (int j = 0; j < 4; ++j) bf[j] = frag(Bc, wn + 16 * j + l16, quad);
    if (t + 1 < NSTEP) {
      #pragma unroll
      for (int o = 0; o < 4; ++o) stageB(Bn, t + 1, o);
    }
    __builtin_amdgcn_s_setprio(1);
    #pragma unroll
    for (int i = 0; i < 4; ++i)
      #pragma unroll
      for (int j = 0; j < 4; ++j)
        acc[i][j] = __builtin_amdgcn_mfma_f32_16x16x32_f16(af[i], bf[j], acc[i][j], 0, 0, 0);
    __builtin_amdgcn_s_setprio(0);
    #pragma unroll
    for (int i = 0; i < 4; ++i) af[i] = frag(Ac, wm + 16 * i + l16, 4 + quad);
    #pragma unroll
    for (int j = 0; j < 4; ++j) bf[j] = frag(Bc, wn + 16 * j + l16, 4 + quad);
    asm volatile("s_waitcnt lgkmcnt(0)" ::: "memory");
    asm volatile("s_barrier" ::: "memory");
    __builtin_amdgcn_s_setprio(1);
    #pragma unroll
    for (int i = 0; i < 4; ++i)
      #pragma unroll
      for (int j = 0; j < 4; ++j)
        acc[i][j] = __builtin_amdgcn_mfma_f32_16x16x32_f16(af[i], bf[j], acc[i][j], 0, 0, 0);
    __builtin_amdgcn_s_setprio(0);

    char* tmp;
    tmp = Ac; Ac = An; An = tmp;
    tmp = Bc; Bc = Bn; Bn = tmp;
  }

  #pragma unroll
  for (int i = 0; i < 4; ++i) {
    int mb = r0 + wm + 16 * i + quad * 4;
    #pragma unroll
    for (int j = 0; j < 4; ++j) {
      int col = n0 + wn + 16 * j + l16;
      #pragma unroll
      for (int rg = 0; rg < 4; ++rg)
        hb2[(size_t)(mb + rg) * EMBED + col] = (_Float16)acc[i][j][rg];
    }
  }
}

// ---------------------------------------------------------------------------
// Combine: out[t] = hb2[inv[2t]] + hb2[inv[2t+1]] (fp32 out).
// ---------------------------------------------------------------------------
__global__ __launch_bounds__(256) void combine_kernel(
    const _Float16* __restrict__ hb2, const int* __restrict__ inv,
    float* __restrict__ out)
{
  int t = blockIdx.x;
  int d = threadIdx.x * 4;
  int p0 = inv[2 * t], p1 = inv[2 * t + 1];
  f16x4 a = *(const f16x4*)(hb2 + (size_t)p0 * EMBED + d);
  f16x4 b = *(const f16x4*)(hb2 + (size_t)p1 * EMBED + d);
  float4 r;
  r.x = (float)a.x + (float)b.x;
  r.y = (float)a.y + (float)b.y;
  r.z = (float)a.z + (float)b.z;
  r.w = (float)a.w + (float)b.w;
  *(float4*)(out + (size_t)t * EMBED + d) = r;
}

// ---------------------------------------------------------------------------
extern "C" void kernel_launch(void* const* d_in, const int* in_sizes, int n_in,
                              void* d_out, int out_size, void* d_ws, size_t ws_size,
                              hipStream_t stream)
{
  (void)in_sizes; (void)n_in; (void)ws_size; (void)out_size;
  const float* x  = (const float*)d_in[0];
  const float* gw = (const float*)d_in[1];
  const float* w1 = (const float*)d_in[2];
  const float* w2 = (const float*)d_in[3];   // NOTE: dict order is w1, w2, w3
  const float* w3 = (const float*)d_in[4];
  float* out = (float*)d_out;
  char* ws = (char*)d_ws;

  size_t o = 0;
  auto alloc = [&](size_t bytes) { size_t r = o; o = (o + bytes + 255) & ~255ULL; return r; };
  _Float16* w13t = (_Float16*)(ws + alloc((size_t)NE * MLP2 * EMBED * 2));
  _Float16* w2t  = (_Float16*)(ws + alloc((size_t)NE * MLP * EMBED * 2));
  _Float16* xg   = (_Float16*)(ws + alloc((size_t)RMAX * EMBED * 2));
  _Float16* hb   = (_Float16*)(ws + alloc((size_t)RMAX * MLP * 2));
  int*   rowtok  = (int*)(ws + alloc((size_t)RMAX * 4));
  float* rowcoef = (float*)(ws + alloc((size_t)RMAX * 4));
  int*   sel_e   = (int*)(ws + alloc((size_t)2 * NTOK * 4));
  float* sel_w   = (float*)(ws + alloc((size_t)2 * NTOK * 4));
  int*   inv     = (int*)(ws + alloc((size_t)2 * NTOK * 4));
  int*   meta    = (int*)(ws + alloc(256));
  int* counts = meta;          // [8]
  int* offs   = meta + 8;      // [9]
  int* cursor = meta + 17;     // [8] (zero-based)
  // hb2 aliases xg: xg is dead after gemm1; both are RMAX*EMBED fp16.
  _Float16* hb2 = xg;

  hipMemsetAsync(meta, 0, 256, stream);
  hipMemsetAsync(rowtok, 0xFF, (size_t)RMAX * 4, stream);   // -1 = padding
  hipMemsetAsync(rowcoef, 0, (size_t)RMAX * 4, stream);

  transpose_all_kernel<<<3 * 4096, 256, 0, stream>>>(w1, w3, w2, w13t, w2t);

  router_kernel<<<NTOK / 4, 256, 0, stream>>>(x, gw, sel_e, sel_w, counts);
  assign_kernel<<<NTOK / 256, 256, 0, stream>>>(sel_e, sel_w, counts, cursor,
                                                offs, rowtok, rowcoef, inv);
  gather_kernel<<<RMAX, 256, 0, stream>>>(x, rowtok, xg);

  gemm1_kernel<<<dim3(RMAX / 256, MLP2 / 256), 512, 0, stream>>>(xg, w13t, rowcoef, offs, hb);
  gemm2_kernel<<<dim3(RMAX / 128, EMBED / 256), 512, 0, stream>>>(hb, w2t, offs, hb2);
  combine_kernel<<<NTOK, 256, 0, stream>>>(hb2, inv, out);
}